// Round 6
// baseline (201.620 us; speedup 1.0000x reference)
//
#include <hip/hip_runtime.h>

#define NB     8      // batches
#define NP     2048   // points per cloud
#define NITER  8
#define NWG    256    // grid (coop-launch proven at 256)
#define NT     512    // threads per workgroup (8 waves)
#define TSTEPS 32     // targets per lane = NP / 64
#define WPBMAX 64     // max team size we support (LDS caps real co-residency below this)

// ws float layout:
//   slots : [NB][2 parity][WPBMAX][16]   (word 0..14 partials, word 15 uint tag)
//   bcast : [NB][16]                     (word 0..8 R, 9..11 t, 15 uint tag)
//   reg   : cnt[8] uint, gctr uint       (agent-scope registration, one-time)
// Entire region hipMemsetAsync(0) per call -> replay-deterministic.
#define SLOTS_FLOATS (NB*2*WPBMAX*16)            // 16384
#define BCAST_FBASE  SLOTS_FLOATS
#define REG_FBASE    (SLOTS_FLOATS + NB*16)
#define WS_FLOATS    (REG_FBASE + 16)

// Same-XCD communication protocol (teams are discovered via HW_REG_XCC_ID so
// all members share one L2): writers use plain stores (CDNA L1 is write-through
// -> dirty in the shared L2), then s_waitcnt vmcnt(0), then a volatile tag
// store. Readers poll the tag with volatile loads (L1-bypass, L2-hit) and then
// volatile-load the data. No agent fences / no cache maintenance in the loop.
__device__ __forceinline__ float    vldf(const float* p)            { return *(volatile const float*)p; }
__device__ __forceinline__ void     vstf(float* p, float v)         { *(volatile float*)p = v; }
__device__ __forceinline__ unsigned vldu(const unsigned* p)         { return *(volatile const unsigned*)p; }
__device__ __forceinline__ void     vstu(unsigned* p, unsigned v)   { *(volatile unsigned*)p = v; }
__device__ __forceinline__ void     waitvm()                        { asm volatile("s_waitcnt vmcnt(0)" ::: "memory"); }

// Orthogonal polar factor of M (== U @ Vh of the SVD) in fp32, with the
// reference's reflection handling (R = -R when det = -1). Det-scaled Newton.
__device__ void polar3x3f(const float* Min, float* R) {
  float X[9];
  #pragma unroll
  for (int i = 0; i < 9; ++i) X[i] = Min[i];
  #pragma unroll 1
  for (int it = 0; it < 12; ++it) {
    const float C0 = X[4]*X[8]-X[5]*X[7];
    const float C1 = X[5]*X[6]-X[3]*X[8];
    const float C2 = X[3]*X[7]-X[4]*X[6];
    const float C3 = X[2]*X[7]-X[1]*X[8];
    const float C4 = X[0]*X[8]-X[2]*X[6];
    const float C5 = X[1]*X[6]-X[0]*X[7];
    const float C6 = X[1]*X[5]-X[2]*X[4];
    const float C7 = X[2]*X[3]-X[0]*X[5];
    const float C8 = X[0]*X[4]-X[1]*X[3];
    const float det = X[0]*C0 + X[1]*C1 + X[2]*C2;
    const float ad  = fabsf(det);
    const float g   = (ad > 1e-30f) ? exp2f(-0.33333333333f * log2f(ad)) : 1.0f;
    const float ds  = (ad > 1e-30f) ? det : 1e-30f;
    const float h   = 0.5f / (g * ds);     // X' = 0.5*g*X + cof(X)/(2*g*det)
    const float gh  = 0.5f * g;
    X[0]=gh*X[0]+h*C0; X[1]=gh*X[1]+h*C1; X[2]=gh*X[2]+h*C2;
    X[3]=gh*X[3]+h*C3; X[4]=gh*X[4]+h*C4; X[5]=gh*X[5]+h*C5;
    X[6]=gh*X[6]+h*C6; X[7]=gh*X[7]+h*C7; X[8]=gh*X[8]+h*C8;
  }
  const float d = X[0]*(X[4]*X[8]-X[5]*X[7])
                + X[1]*(X[5]*X[6]-X[3]*X[8])
                + X[2]*(X[3]*X[7]-X[4]*X[6]);
  const float s = (d < 0.0f) ? -1.0f : 1.0f;
  #pragma unroll
  for (int i = 0; i < 9; ++i) R[i] = s * X[i];
}

__global__ __launch_bounds__(NT, 2)
void icp_kernel(const float* __restrict__ src, const float* __restrict__ tgt,
                float* __restrict__ out, float* __restrict__ ws)
{
  __shared__ float4 s_tgt[NP];        // 32 KB: {x,y,z, 0.5*|t|^2}
  __shared__ float  s_tmp3[NP*3];     // 24 KB: this WG's temporal chunk (worst case)
  __shared__ float  s_part[8][16];    // per-wave partial sums
  __shared__ float  s_rt[12];         // R (9) + t (3) broadcast within WG
  __shared__ int    s_info[4];        // rank, teamsize, teamindex, nteams

  const int tid  = threadIdx.x;
  const int wave = tid >> 6;
  const int lane = tid & 63;

  // ---- one-time registration: discover XCD placement, form teams (agent) ----
  if (tid == 0) {
    unsigned x;
    asm volatile("s_getreg_b32 %0, hwreg(HW_REG_XCC_ID)" : "=s"(x));
    const int myxcd = (int)(x & 7u);
    unsigned* reg = (unsigned*)(ws + REG_FBASE);
    const unsigned rank =
        __hip_atomic_fetch_add(&reg[myxcd], 1u, __ATOMIC_RELAXED, __HIP_MEMORY_SCOPE_AGENT);
    waitvm();  // cnt-add acked at coherence point before arrival ticks
    __hip_atomic_fetch_add(&reg[8], 1u, __ATOMIC_ACQ_REL, __HIP_MEMORY_SCOPE_AGENT);
    int guard = 0;
    while (__hip_atomic_load(&reg[8], __ATOMIC_RELAXED, __HIP_MEMORY_SCOPE_AGENT) < (unsigned)NWG) {
      __builtin_amdgcn_s_sleep(8);
      if (++guard > (1 << 20)) break;   // fail visibly, never wedge
    }
    unsigned cc[8];
    #pragma unroll
    for (int i = 0; i < 8; ++i)
      cc[i] = __hip_atomic_load(&reg[i], __ATOMIC_RELAXED, __HIP_MEMORY_SCOPE_AGENT);
    int nteams = 0, tix = 0;
    #pragma unroll
    for (int i = 0; i < 8; ++i)
      if (cc[i] > 0u) { if (i < myxcd) ++tix; ++nteams; }
    s_info[0] = (int)rank;
    s_info[1] = (int)cc[myxcd];
    s_info[2] = tix;
    s_info[3] = nteams;
  }
  __syncthreads();

  const int rank   = s_info[0];
  const int myc    = (s_info[1] > WPBMAX) ? WPBMAX : s_info[1];
  const int tix    = s_info[2];
  const int nteams = (s_info[3] > 0) ? s_info[3] : 1;
  if (rank >= myc) return;            // overflow ranks idle (whole-WG uniform)
  const bool isServer = (rank == 0);

  // team tix handles batches b = tix, tix+nteams, ... (1:1 when all 8 XCDs host WGs)
  for (int b = tix; b < NB; b += nteams) {
    __syncthreads();                  // LDS reuse safety across batches

    // ---- stage targets; .w = 0.5*|t|^2 for the score trick ----
    const float* tb = tgt + (size_t)b * NP * 3;
    for (int i = tid; i < NP; i += NT) {
      const float tx = tb[3*i+0], ty = tb[3*i+1], tz = tb[3*i+2];
      s_tgt[i] = make_float4(tx, ty, tz, 0.5f*(tx*tx + ty*ty + tz*tz));
    }
    // ---- stage this WG's temporal chunk [cs, ce) into LDS ----
    const int cs = (NP * rank) / myc;
    const int ce = (NP * (rank + 1)) / myc;
    const int n3 = (ce - cs) * 3;
    const float* sbp = src + ((size_t)b * NP + cs) * 3;
    for (int i = tid; i < n3; i += NT) s_tmp3[i] = sbp[i];
    __syncthreads();

    float Rtot[9] = {1.f,0.f,0.f, 0.f,1.f,0.f, 0.f,0.f,1.f};
    float ttot[3] = {0.f,0.f,0.f};
    float* bl = ws + BCAST_FBASE + b * 16;

    for (int round = 0; round < NITER; ++round) {
      const int      par  = round & 1;
      const unsigned want = (unsigned)(round + 1);

      // ---- KNN + Kabsch partials over this WG's tiles (8 refs/wave/tile) ----
      float S[15];
      #pragma unroll
      for (int i = 0; i < 15; ++i) S[i] = 0.f;

      for (int base = cs + wave * 8; base < ce; base += 64) {
        const int nref = min(8, ce - base);
        const int lb   = base - cs;
        float px[8], py[8], pz[8];
        #pragma unroll
        for (int r = 0; r < 8; ++r) {
          const int rr = (r < nref) ? r : (nref - 1);   // clamp (excluded below)
          const int l  = 3 * (lb + rr);
          px[r] = s_tmp3[l]; py[r] = s_tmp3[l+1]; pz[r] = s_tmp3[l+2];
        }
        float bs[8]; int bj[8];
        #pragma unroll
        for (int r = 0; r < 8; ++r) { bs[r] = 3.4e38f; bj[r] = 0; }
        #pragma unroll 4
        for (int k = 0; k < TSTEPS; ++k) {
          const int j = k * 64 + lane;
          const float4 tp = s_tgt[j];
          #pragma unroll
          for (int r = 0; r < 8; ++r) {
            const float sc = fmaf(-px[r], tp.x, fmaf(-py[r], tp.y, fmaf(-pz[r], tp.z, tp.w)));
            if (sc < bs[r]) { bs[r] = sc; bj[r] = j; }   // strict < keeps first index
          }
        }
        #pragma unroll
        for (int r = 0; r < 8; ++r) {
          #pragma unroll
          for (int sh = 0; sh < 6; ++sh) {
            const int   off = 32 >> sh;
            const float od  = __shfl_xor(bs[r], off);
            const int   oj  = __shfl_xor(bj[r], off);
            if (od < bs[r] || (od == bs[r] && oj < bj[r])) { bs[r] = od; bj[r] = oj; }
          }
        }
        #pragma unroll
        for (int r = 0; r < 8; ++r) {
          if (r < nref) {                       // wave-uniform bound
            const float4 tm = s_tgt[bj[r]];
            S[0]+=px[r]; S[1]+=py[r]; S[2]+=pz[r];
            S[3]+=tm.x;  S[4]+=tm.y;  S[5]+=tm.z;
            S[6] +=tm.x*px[r]; S[7] +=tm.x*py[r]; S[8] +=tm.x*pz[r];
            S[9] +=tm.y*px[r]; S[10]+=tm.y*py[r]; S[11]+=tm.y*pz[r];
            S[12]+=tm.z*px[r]; S[13]+=tm.z*py[r]; S[14]+=tm.z*pz[r];
          }
        }
      }
      if (lane == 0) {
        #pragma unroll
        for (int i = 0; i < 15; ++i) s_part[wave][i] = S[i];
      }
      __syncthreads();

      if (wave == 0) {
        // fold 8 wave-partials: afterwards every lane holds S_total[lane&15]
        const int comp = lane & 15, grp = lane >> 4;
        float v = (comp < 15) ? (s_part[2*grp][comp] + s_part[2*grp+1][comp]) : 0.f;
        v += __shfl_xor(v, 16);
        v += __shfl_xor(v, 32);

        // publish own slot (all ranks, incl. server): L2-local stores + tag
        float* slot = ws + (size_t)(((b * 2 + par) * WPBMAX + rank)) * 16;
        if (lane < 15) vstf(&slot[lane], v);
        waitvm();
        if (lane == 0) vstu((unsigned*)slot + 15, want);

        if (isServer) {
          // poll all team slots (lane q watches slot q), then gather
          float* sbase = ws + (size_t)((b * 2 + par) * WPBMAX) * 16;
          unsigned* tagq = (unsigned*)(sbase + (size_t)lane * 16) + 15;
          int ok, guard = 0;
          do {
            ok = (lane >= myc) || (vldu(tagq) == want);
            if (++guard > (1 << 21)) break;
          } while (!__all(ok));

          const float* slotq = sbase + (size_t)lane * 16;
          float s[15];
          #pragma unroll
          for (int i = 0; i < 15; ++i)
            s[i] = (lane < myc) ? vldf(&slotq[i]) : 0.f;
          #pragma unroll
          for (int i = 0; i < 15; ++i) {
            s[i] += __shfl_xor(s[i], 1);
            s[i] += __shfl_xor(s[i], 2);
            s[i] += __shfl_xor(s[i], 4);
            s[i] += __shfl_xor(s[i], 8);
            s[i] += __shfl_xor(s[i], 16);
            s[i] += __shfl_xor(s[i], 32);
          }

          if (lane == 0) {
            const double inv = 1.0 / (double)NP;
            const double cs0=(double)s[0]*inv, cs1=(double)s[1]*inv, cs2=(double)s[2]*inv;
            const double ct0=(double)s[3]*inv, ct1=(double)s[4]*inv, ct2=(double)s[5]*inv;
            float M[9];
            M[0]=(float)((double)s[6] -(double)NP*ct0*cs0); M[1]=(float)((double)s[7] -(double)NP*ct0*cs1); M[2]=(float)((double)s[8] -(double)NP*ct0*cs2);
            M[3]=(float)((double)s[9] -(double)NP*ct1*cs0); M[4]=(float)((double)s[10]-(double)NP*ct1*cs1); M[5]=(float)((double)s[11]-(double)NP*ct1*cs2);
            M[6]=(float)((double)s[12]-(double)NP*ct2*cs0); M[7]=(float)((double)s[13]-(double)NP*ct2*cs1); M[8]=(float)((double)s[14]-(double)NP*ct2*cs2);
            float R[9]; polar3x3f(M, R);
            const float t0 = (float)(ct0 - ((double)R[0]*cs0 + (double)R[1]*cs1 + (double)R[2]*cs2));
            const float t1 = (float)(ct1 - ((double)R[3]*cs0 + (double)R[4]*cs1 + (double)R[5]*cs2));
            const float t2 = (float)(ct2 - ((double)R[6]*cs0 + (double)R[7]*cs1 + (double)R[8]*cs2));

            if (round < NITER - 1) {
              #pragma unroll
              for (int i = 0; i < 9; ++i) vstf(&bl[i], R[i]);
              vstf(&bl[9], t0); vstf(&bl[10], t1); vstf(&bl[11], t2);
              waitvm();
              vstu((unsigned*)bl + 15, want);
              s_rt[0]=R[0]; s_rt[1]=R[1]; s_rt[2]=R[2];
              s_rt[3]=R[3]; s_rt[4]=R[4]; s_rt[5]=R[5];
              s_rt[6]=R[6]; s_rt[7]=R[7]; s_rt[8]=R[8];
              s_rt[9]=t0;  s_rt[10]=t1;  s_rt[11]=t2;
            }

            // compose total transform: T_tot <- T_round ∘ T_tot
            float Rn[9], tn[3];
            #pragma unroll
            for (int i = 0; i < 3; ++i) {
              Rn[3*i+0] = R[3*i+0]*Rtot[0] + R[3*i+1]*Rtot[3] + R[3*i+2]*Rtot[6];
              Rn[3*i+1] = R[3*i+0]*Rtot[1] + R[3*i+1]*Rtot[4] + R[3*i+2]*Rtot[7];
              Rn[3*i+2] = R[3*i+0]*Rtot[2] + R[3*i+1]*Rtot[5] + R[3*i+2]*Rtot[8];
              tn[i]     = R[3*i+0]*ttot[0] + R[3*i+1]*ttot[1] + R[3*i+2]*ttot[2]
                        + ((i==0)?t0:(i==1)?t1:t2);
            }
            #pragma unroll
            for (int i = 0; i < 9; ++i) Rtot[i] = Rn[i];
            ttot[0]=tn[0]; ttot[1]=tn[1]; ttot[2]=tn[2];

            if (round == NITER - 1) {
              // svdtf(source, temporal_8) == composed transform (exact rigid)
              float* ob = out + b * 12;
              ob[0]=Rtot[0]; ob[1]=Rtot[1]; ob[2] =Rtot[2]; ob[3] =ttot[0];
              ob[4]=Rtot[3]; ob[5]=Rtot[4]; ob[6] =Rtot[5]; ob[7] =ttot[1];
              ob[8]=Rtot[6]; ob[9]=Rtot[7]; ob[10]=Rtot[8]; ob[11]=ttot[2];
            }
          }
        } else if (round < NITER - 1) {
          // worker: spin on the team broadcast line (L2-hit volatile loads)
          unsigned* btag = (unsigned*)bl + 15;
          int guard = 0;
          while (vldu(btag) != want) { if (++guard > (1 << 21)) break; }
          if (lane < 12) s_rt[lane] = vldf(&bl[lane]);
        }
      }

      if (round < NITER - 1) {
        __syncthreads();
        // ---- apply transform to own temporal chunk (lane r owns point r of tile) ----
        const float R00=s_rt[0],R01=s_rt[1],R02=s_rt[2],
                    R10=s_rt[3],R11=s_rt[4],R12=s_rt[5],
                    R20=s_rt[6],R21=s_rt[7],R22=s_rt[8],
                    t0=s_rt[9], t1=s_rt[10], t2=s_rt[11];
        for (int base = cs + wave * 8; base < ce; base += 64) {
          const int nref = min(8, ce - base);
          if (lane < nref) {
            const int l = 3 * (base - cs + lane);
            const float x = s_tmp3[l], y = s_tmp3[l+1], z = s_tmp3[l+2];
            s_tmp3[l]   = t0 + R00*x + R01*y + R02*z;
            s_tmp3[l+1] = t1 + R10*x + R11*y + R12*z;
            s_tmp3[l+2] = t2 + R20*x + R21*y + R22*z;
          }
        }
      }
      // last round: workers only publish; server composes and writes output.
    }
  }
}

extern "C" void kernel_launch(void* const* d_in, const int* in_sizes, int n_in,
                              void* d_out, int out_size, void* d_ws, size_t ws_size,
                              hipStream_t stream)
{
  const float* src = (const float*)d_in[0];
  const float* tgt = (const float*)d_in[1];
  float* out = (float*)d_out;
  float* ws  = (float*)d_ws;

  // zero slots + bcast + registration each call: deterministic across replays
  hipMemsetAsync(d_ws, 0, WS_FLOATS * sizeof(float), stream);

  void* args[] = { (void*)&src, (void*)&tgt, (void*)&out, (void*)&ws };
  hipLaunchCooperativeKernel(reinterpret_cast<void*>(icp_kernel),
                             dim3(NWG), dim3(NT), args, 0, stream);
}

// Round 7
// 151.680 us; speedup vs baseline: 1.3292x; 1.3292x over previous
//
#include <hip/hip_runtime.h>

#define NB     8      // batches
#define NP     2048   // points per cloud
#define NITER  8
#define TEAM   32     // WGs per XCD-team (1 WG/CU enforced => exactly 32 WGs/XCD)
#define NWG    256    // cooperative grid (1 WG per CU)
#define NT     512    // threads per workgroup (8 waves)
#define TSTEPS 32     // targets per lane = NP / 64

// ws float layout:
//   slots : [NB][2 parity][TEAM][16]  (word 0..14 partials, word 15 uint tag)
//   reg   : 8 uints (per-XCD rank counters, relaxed agent fetch_add, one-time)
// Entire region hipMemsetAsync(0) per call -> replay-deterministic.
#define SLOTS_FLOATS (NB*2*TEAM*16)   // 8192
#define REG_FBASE    SLOTS_FLOATS
#define WS_FLOATS    (REG_FBASE + 8)

// Same-XCD protocol (team members share one L2 by construction): writers use
// plain write-through stores, s_waitcnt vmcnt(0), then a volatile tag store.
// Readers poll the tag volatile (L1-bypass, hits the shared L2), then
// volatile-load the data. Proven correct+local in round 6 (WRITE_SIZE 4.4x drop).
__device__ __forceinline__ float    vldf(const float* p)          { return *(volatile const float*)p; }
__device__ __forceinline__ void     vstf(float* p, float v)       { *(volatile float*)p = v; }
__device__ __forceinline__ unsigned vldu(const unsigned* p)       { return *(volatile const unsigned*)p; }
__device__ __forceinline__ void     vstu(unsigned* p, unsigned v) { *(volatile unsigned*)p = v; }
__device__ __forceinline__ void     waitvm()                      { asm volatile("s_waitcnt vmcnt(0)" ::: "memory"); }

// Orthogonal polar factor of M (== U @ Vh of the SVD) in fp32, with the
// reference's reflection handling (R = -R when det = -1). Det-scaled Newton.
__device__ void polar3x3f(const float* Min, float* R) {
  float X[9];
  #pragma unroll
  for (int i = 0; i < 9; ++i) X[i] = Min[i];
  #pragma unroll 1
  for (int it = 0; it < 12; ++it) {
    const float C0 = X[4]*X[8]-X[5]*X[7];
    const float C1 = X[5]*X[6]-X[3]*X[8];
    const float C2 = X[3]*X[7]-X[4]*X[6];
    const float C3 = X[2]*X[7]-X[1]*X[8];
    const float C4 = X[0]*X[8]-X[2]*X[6];
    const float C5 = X[1]*X[6]-X[0]*X[7];
    const float C6 = X[1]*X[5]-X[2]*X[4];
    const float C7 = X[2]*X[3]-X[0]*X[5];
    const float C8 = X[0]*X[4]-X[1]*X[3];
    const float det = X[0]*C0 + X[1]*C1 + X[2]*C2;
    const float ad  = fabsf(det);
    const float g   = (ad > 1e-30f) ? exp2f(-0.33333333333f * log2f(ad)) : 1.0f;
    const float ds  = (ad > 1e-30f) ? det : 1e-30f;
    const float h   = 0.5f / (g * ds);     // X' = 0.5*g*X + cof(X)/(2*g*det)
    const float gh  = 0.5f * g;
    X[0]=gh*X[0]+h*C0; X[1]=gh*X[1]+h*C1; X[2]=gh*X[2]+h*C2;
    X[3]=gh*X[3]+h*C3; X[4]=gh*X[4]+h*C4; X[5]=gh*X[5]+h*C5;
    X[6]=gh*X[6]+h*C6; X[7]=gh*X[7]+h*C7; X[8]=gh*X[8]+h*C8;
  }
  const float d = X[0]*(X[4]*X[8]-X[5]*X[7])
                + X[1]*(X[5]*X[6]-X[3]*X[8])
                + X[2]*(X[3]*X[7]-X[4]*X[6]);
  const float s = (d < 0.0f) ? -1.0f : 1.0f;
  #pragma unroll
  for (int i = 0; i < 9; ++i) R[i] = s * X[i];
}

__global__ __launch_bounds__(NT)
__attribute__((amdgpu_waves_per_eu(2, 2)))   // cap 8 waves/CU -> exactly 1 WG/CU
void icp_kernel(const float* __restrict__ src, const float* __restrict__ tgt,
                float* __restrict__ out, float* __restrict__ ws)
{
  __shared__ float4 s_tgt[NP];        // 32 KB: {x,y,z, 0.5*|t|^2}
  __shared__ float  s_part[8][16];    // per-wave partial sums
  __shared__ float  s_rt[12];         // R (9) + t (3) broadcast within WG
  __shared__ int    s_rank;

  const int tid  = threadIdx.x;
  const int wave = tid >> 6;
  const int lane = tid & 63;

  // XCD id (wave-uniform scalar; identical across the WG's waves)
  unsigned xcc;
  asm volatile("s_getreg_b32 %0, hwreg(HW_REG_XCC_ID)" : "=s"(xcc));
  const int batch = (int)(xcc & 7u);  // team == XCD == batch (1:1, 8 each)

  // one-time rank: relaxed fetch_add on THIS XCD's counter (8 independent
  // lines, max 32 serialized adds each). Latency hides under target staging.
  if (tid == 0) {
    unsigned* reg = (unsigned*)(ws + REG_FBASE);
    const unsigned rk =
        __hip_atomic_fetch_add(&reg[batch], 1u, __ATOMIC_RELAXED, __HIP_MEMORY_SCOPE_AGENT);
    s_rank = (int)(rk & 31u);
  }

  // ---- stage targets; .w = 0.5*|t|^2 for the score trick ----
  const float* tb = tgt + (size_t)batch * NP * 3;
  for (int i = tid; i < NP; i += NT) {
    const float tx = tb[3*i+0], ty = tb[3*i+1], tz = tb[3*i+2];
    s_tgt[i] = make_float4(tx, ty, tz, 0.5f*(tx*tx + ty*ty + tz*tz));
  }
  __syncthreads();

  const int  rank = s_rank;           // 0..31 within this XCD's team
  const bool lead = (rank == 0);

  // ---- this wave's 8 temporal points (replicated across lanes, registers) ----
  const int r0 = rank * 64 + wave * 8;
  const float* sb = src + (size_t)(batch * NP + r0) * 3;
  float px[8], py[8], pz[8];
  #pragma unroll
  for (int r = 0; r < 8; ++r) {
    px[r] = sb[3*r+0]; py[r] = sb[3*r+1]; pz[r] = sb[3*r+2];
  }

  float Rtot[9] = {1.f,0.f,0.f, 0.f,1.f,0.f, 0.f,0.f,1.f};
  float ttot[3] = {0.f,0.f,0.f};

  for (int round = 0; round < NITER; ++round) {
    const int      par  = round & 1;
    const unsigned want = (unsigned)(round + 1);

    // ---- KNN via score = 0.5|t|^2 - p.t  (argmin(score) == argmin(dist)) ----
    float bs[8]; int bj[8];
    #pragma unroll
    for (int r = 0; r < 8; ++r) { bs[r] = 3.4e38f; bj[r] = 0; }
    #pragma unroll 4
    for (int k = 0; k < TSTEPS; ++k) {
      const int j = k * 64 + lane;
      const float4 tp = s_tgt[j];
      #pragma unroll
      for (int r = 0; r < 8; ++r) {
        const float sc = fmaf(-px[r], tp.x, fmaf(-py[r], tp.y, fmaf(-pz[r], tp.z, tp.w)));
        if (sc < bs[r]) { bs[r] = sc; bj[r] = j; }   // strict < keeps first index
      }
    }
    // cross-lane argmin, tie -> smaller index (matches argmin first-index rule)
    #pragma unroll
    for (int r = 0; r < 8; ++r) {
      #pragma unroll
      for (int sh = 0; sh < 6; ++sh) {
        const int   off = 32 >> sh;
        const float od  = __shfl_xor(bs[r], off);
        const int   oj  = __shfl_xor(bj[r], off);
        if (od < bs[r] || (od == bs[r] && oj < bj[r])) { bs[r] = od; bj[r] = oj; }
      }
    }

    // ---- per-wave Kabsch partials (identical in every lane; lane 0 writes) ----
    {
      float S[15];
      #pragma unroll
      for (int i = 0; i < 15; ++i) S[i] = 0.f;
      #pragma unroll
      for (int r = 0; r < 8; ++r) {
        const float4 tm = s_tgt[bj[r]];
        S[0]+=px[r]; S[1]+=py[r]; S[2]+=pz[r];
        S[3]+=tm.x;  S[4]+=tm.y;  S[5]+=tm.z;
        S[6] +=tm.x*px[r]; S[7] +=tm.x*py[r]; S[8] +=tm.x*pz[r];
        S[9] +=tm.y*px[r]; S[10]+=tm.y*py[r]; S[11]+=tm.y*pz[r];
        S[12]+=tm.z*px[r]; S[13]+=tm.z*py[r]; S[14]+=tm.z*pz[r];
      }
      if (lane == 0) {
        #pragma unroll
        for (int i = 0; i < 15; ++i) s_part[wave][i] = S[i];
      }
    }
    __syncthreads();

    if (wave == 0) {
      // fold 8 wave-partials: every lane ends with S_total[lane & 15]
      const int comp = lane & 15, grp = lane >> 4;
      float v = (comp < 15) ? (s_part[2*grp][comp] + s_part[2*grp+1][comp]) : 0.f;
      v += __shfl_xor(v, 16);
      v += __shfl_xor(v, 32);

      // publish own slot: L2-local stores + ack + tag
      float* slot = ws + ((((size_t)batch * 2 + par) * TEAM + rank) << 4);
      if (lane < 15) vstf(&slot[lane], v);
      waitvm();
      if (lane == 0) vstu((unsigned*)slot + 15, want);

      // redundant reduce in every WG (last round: lead only)
      if ((round < NITER - 1) || lead) {
        float* sbase = ws + (((size_t)batch * 2 + par) * TEAM << 4);
        unsigned* tagq = (unsigned*)(sbase + ((size_t)lane << 4)) + 15;
        int ok, guard = 0;
        do {
          ok = (lane >= TEAM) || (vldu(tagq) == want);
          if (++guard > (1 << 15)) break;   // fail visibly, never wedge
        } while (!__all(ok));

        const float* slotq = sbase + ((size_t)lane << 4);
        float s[15];
        #pragma unroll
        for (int i = 0; i < 15; ++i)
          s[i] = (lane < TEAM) ? vldf(&slotq[i]) : 0.f;
        #pragma unroll
        for (int i = 0; i < 15; ++i) {
          s[i] += __shfl_xor(s[i], 1);
          s[i] += __shfl_xor(s[i], 2);
          s[i] += __shfl_xor(s[i], 4);
          s[i] += __shfl_xor(s[i], 8);
          s[i] += __shfl_xor(s[i], 16);
        }

        if (lane == 0) {
          const double inv = 1.0 / (double)NP;
          const double cs0=(double)s[0]*inv, cs1=(double)s[1]*inv, cs2=(double)s[2]*inv;
          const double ct0=(double)s[3]*inv, ct1=(double)s[4]*inv, ct2=(double)s[5]*inv;
          float M[9];
          M[0]=(float)((double)s[6] -(double)NP*ct0*cs0); M[1]=(float)((double)s[7] -(double)NP*ct0*cs1); M[2]=(float)((double)s[8] -(double)NP*ct0*cs2);
          M[3]=(float)((double)s[9] -(double)NP*ct1*cs0); M[4]=(float)((double)s[10]-(double)NP*ct1*cs1); M[5]=(float)((double)s[11]-(double)NP*ct1*cs2);
          M[6]=(float)((double)s[12]-(double)NP*ct2*cs0); M[7]=(float)((double)s[13]-(double)NP*ct2*cs1); M[8]=(float)((double)s[14]-(double)NP*ct2*cs2);
          float R[9]; polar3x3f(M, R);
          const float t0 = (float)(ct0 - ((double)R[0]*cs0 + (double)R[1]*cs1 + (double)R[2]*cs2));
          const float t1 = (float)(ct1 - ((double)R[3]*cs0 + (double)R[4]*cs1 + (double)R[5]*cs2));
          const float t2 = (float)(ct2 - ((double)R[6]*cs0 + (double)R[7]*cs1 + (double)R[8]*cs2));

          s_rt[0]=R[0]; s_rt[1]=R[1]; s_rt[2]=R[2];
          s_rt[3]=R[3]; s_rt[4]=R[4]; s_rt[5]=R[5];
          s_rt[6]=R[6]; s_rt[7]=R[7]; s_rt[8]=R[8];
          s_rt[9]=t0;  s_rt[10]=t1;  s_rt[11]=t2;

          if (lead) {
            // compose total transform: T_tot <- T_round ∘ T_tot
            float Rn[9], tn[3];
            #pragma unroll
            for (int i = 0; i < 3; ++i) {
              Rn[3*i+0] = R[3*i+0]*Rtot[0] + R[3*i+1]*Rtot[3] + R[3*i+2]*Rtot[6];
              Rn[3*i+1] = R[3*i+0]*Rtot[1] + R[3*i+1]*Rtot[4] + R[3*i+2]*Rtot[7];
              Rn[3*i+2] = R[3*i+0]*Rtot[2] + R[3*i+1]*Rtot[5] + R[3*i+2]*Rtot[8];
              tn[i]     = R[3*i+0]*ttot[0] + R[3*i+1]*ttot[1] + R[3*i+2]*ttot[2]
                        + ((i==0)?t0:(i==1)?t1:t2);
            }
            #pragma unroll
            for (int i = 0; i < 9; ++i) Rtot[i] = Rn[i];
            ttot[0]=tn[0]; ttot[1]=tn[1]; ttot[2]=tn[2];

            if (round == NITER - 1) {
              // svdtf(source, temporal_8) == composed transform (exact rigid,
              // det=+1, so the reference's reflection branch is a no-op)
              float* ob = out + batch * 12;
              ob[0]=Rtot[0]; ob[1]=Rtot[1]; ob[2] =Rtot[2]; ob[3] =ttot[0];
              ob[4]=Rtot[3]; ob[5]=Rtot[4]; ob[6] =Rtot[5]; ob[7] =ttot[1];
              ob[8]=Rtot[6]; ob[9]=Rtot[7]; ob[10]=Rtot[8]; ob[11]=ttot[2];
            }
          }
        }
      }
    }

    if (round < NITER - 1) {
      __syncthreads();
      // ---- apply transform to this wave's temporal points (fp32, like ref) ----
      const float R00=s_rt[0],R01=s_rt[1],R02=s_rt[2],
                  R10=s_rt[3],R11=s_rt[4],R12=s_rt[5],
                  R20=s_rt[6],R21=s_rt[7],R22=s_rt[8],
                  t0=s_rt[9], t1=s_rt[10], t2=s_rt[11];
      #pragma unroll
      for (int r = 0; r < 8; ++r) {
        const float nx = t0 + R00*px[r] + R01*py[r] + R02*pz[r];
        const float ny = t1 + R10*px[r] + R11*py[r] + R12*pz[r];
        const float nz = t2 + R20*px[r] + R21*py[r] + R22*pz[r];
        px[r]=nx; py[r]=ny; pz[r]=nz;
      }
    }
    // last round: publish only; lead composes and writes the output.
  }
}

extern "C" void kernel_launch(void* const* d_in, const int* in_sizes, int n_in,
                              void* d_out, int out_size, void* d_ws, size_t ws_size,
                              hipStream_t stream)
{
  const float* src = (const float*)d_in[0];
  const float* tgt = (const float*)d_in[1];
  float* out = (float*)d_out;
  float* ws  = (float*)d_ws;

  // zero slots + rank counters each call: deterministic across graph replays
  hipMemsetAsync(d_ws, 0, WS_FLOATS * sizeof(float), stream);

  void* args[] = { (void*)&src, (void*)&tgt, (void*)&out, (void*)&ws };
  hipLaunchCooperativeKernel(reinterpret_cast<void*>(icp_kernel),
                             dim3(NWG), dim3(NT), args, 0, stream);
}

// Round 11
// 142.685 us; speedup vs baseline: 1.4130x; 1.0630x over previous
//
#include <hip/hip_runtime.h>

#define NB     8      // batches
#define NP     2048   // points per cloud
#define NITER  8
#define TEAM   32     // WGs per XCD-team (1 WG/CU enforced => exactly 32 WGs/XCD)
#define NWG    256    // cooperative grid (1 WG per CU)
#define NT     512    // threads per workgroup (8 waves)
#define TSTEPS 32     // targets per lane = NP / 64
#define SLOTF  20     // floats per slot: 5 x 16B self-validating quarters

// ws float layout:
//   slots : [NB][2 parity][TEAM][SLOTF]  (5 quarters {d0,d1,d2,tag} each)
//   reg   : 8 uints (per-XCD rank counters, relaxed agent fetch_add, one-time)
// Entire region hipMemsetAsync(0) per call -> replay-deterministic.
#define SLOTS_FLOATS (NB*2*TEAM*SLOTF)   // 10240
#define REG_FBASE    SLOTS_FLOATS
#define WS_FLOATS    (REG_FBASE + 8)

typedef float f32x4 __attribute__((ext_vector_type(4)));

// Comm protocol: TAG-EMBEDDED 16B units at R7's PROVEN scope (sc0+sc1 ==
// volatile). A dwordx4 store is a single 16B transaction, so each quarter
// {3 floats, tag} is self-validating: a load that sees the tag sees its data.
// No writer-side waitcnt, no separate tag store, no second gather round trip.
// (R8/R9's split tag/data plain-store protocol raced -> 2e-2 error; abandoned.
//  R10 note: inline-asm can't take float4 as INPUT operand on gfx950 clang —
//  volatile ext_vector store emits the same global_store_dwordx4 sc0 sc1.)
__device__ __forceinline__ void st_q16(float* p, float x, float y, float z, unsigned tag) {
  f32x4 v = { x, y, z, __uint_as_float(tag) };
  *(volatile f32x4*)p = v;
}
__device__ __forceinline__ void ld_slot5(const float* p, float4& a, float4& b,
                                         float4& c, float4& d, float4& e) {
  asm volatile("global_load_dwordx4 %0, %5, off sc0 sc1\n\t"
               "global_load_dwordx4 %1, %5, off offset:16 sc0 sc1\n\t"
               "global_load_dwordx4 %2, %5, off offset:32 sc0 sc1\n\t"
               "global_load_dwordx4 %3, %5, off offset:48 sc0 sc1\n\t"
               "global_load_dwordx4 %4, %5, off offset:64 sc0 sc1\n\t"
               "s_waitcnt vmcnt(0)"
               : "=&v"(a), "=&v"(b), "=&v"(c), "=&v"(d), "=&v"(e)
               : "v"(p) : "memory");
}

// Orthogonal polar factor of M (== U @ Vh of the SVD) in fp32, with the
// reference's reflection handling (R = -R when det = -1). Det-scaled Newton.
// 12 iterations: proven floor (R2-R7, absmax 7.6e-6). Do NOT trim (R8 lesson).
__device__ void polar3x3f(const float* Min, float* R) {
  float X[9];
  #pragma unroll
  for (int i = 0; i < 9; ++i) X[i] = Min[i];
  #pragma unroll 1
  for (int it = 0; it < 12; ++it) {
    const float C0 = X[4]*X[8]-X[5]*X[7];
    const float C1 = X[5]*X[6]-X[3]*X[8];
    const float C2 = X[3]*X[7]-X[4]*X[6];
    const float C3 = X[2]*X[7]-X[1]*X[8];
    const float C4 = X[0]*X[8]-X[2]*X[6];
    const float C5 = X[1]*X[6]-X[0]*X[7];
    const float C6 = X[1]*X[5]-X[2]*X[4];
    const float C7 = X[2]*X[3]-X[0]*X[5];
    const float C8 = X[0]*X[4]-X[1]*X[3];
    const float det = X[0]*C0 + X[1]*C1 + X[2]*C2;
    const float ad  = fabsf(det);
    const float g   = (ad > 1e-30f) ? exp2f(-0.33333333333f * log2f(ad)) : 1.0f;
    const float ds  = (ad > 1e-30f) ? det : 1e-30f;
    const float h   = 0.5f / (g * ds);     // X' = 0.5*g*X + cof(X)/(2*g*det)
    const float gh  = 0.5f * g;
    X[0]=gh*X[0]+h*C0; X[1]=gh*X[1]+h*C1; X[2]=gh*X[2]+h*C2;
    X[3]=gh*X[3]+h*C3; X[4]=gh*X[4]+h*C4; X[5]=gh*X[5]+h*C5;
    X[6]=gh*X[6]+h*C6; X[7]=gh*X[7]+h*C7; X[8]=gh*X[8]+h*C8;
  }
  const float d = X[0]*(X[4]*X[8]-X[5]*X[7])
                + X[1]*(X[5]*X[6]-X[3]*X[8])
                + X[2]*(X[3]*X[7]-X[4]*X[6]);
  const float s = (d < 0.0f) ? -1.0f : 1.0f;
  #pragma unroll
  for (int i = 0; i < 9; ++i) R[i] = s * X[i];
}

__global__ __launch_bounds__(NT)
__attribute__((amdgpu_waves_per_eu(2, 2)))   // cap 8 waves/CU -> exactly 1 WG/CU
void icp_kernel(const float* __restrict__ src, const float* __restrict__ tgt,
                float* __restrict__ out, float* __restrict__ ws)
{
  __shared__ float4 s_tgt[NP];        // 32 KB: {x,y,z, 0.5*|t|^2}
  __shared__ float  s_part[8][16];    // per-wave partial sums
  __shared__ float  s_rt[12];         // R (9) + t (3) broadcast within WG
  __shared__ int    s_rank;

  const int tid  = threadIdx.x;
  const int wave = tid >> 6;
  const int lane = tid & 63;

  // XCD id (wave-uniform scalar; identical across the WG's waves)
  unsigned xcc;
  asm volatile("s_getreg_b32 %0, hwreg(HW_REG_XCC_ID)" : "=s"(xcc));
  const int batch = (int)(xcc & 7u);  // team == XCD == batch (1:1, 8 each)

  // one-time rank: relaxed fetch_add on THIS XCD's counter (8 independent
  // lines, max 32 serialized adds each). Latency hides under target staging.
  if (tid == 0) {
    unsigned* reg = (unsigned*)(ws + REG_FBASE);
    const unsigned rk =
        __hip_atomic_fetch_add(&reg[batch], 1u, __ATOMIC_RELAXED, __HIP_MEMORY_SCOPE_AGENT);
    s_rank = (int)(rk & 31u);
  }

  // ---- stage targets; .w = 0.5*|t|^2 for the score trick ----
  const float* tb = tgt + (size_t)batch * NP * 3;
  for (int i = tid; i < NP; i += NT) {
    const float tx = tb[3*i+0], ty = tb[3*i+1], tz = tb[3*i+2];
    s_tgt[i] = make_float4(tx, ty, tz, 0.5f*(tx*tx + ty*ty + tz*tz));
  }
  __syncthreads();

  const int  rank = s_rank;           // 0..31 within this XCD's team
  const bool lead = (rank == 0);

  // ---- this wave's 8 temporal points (replicated across lanes, registers) ----
  const int r0 = rank * 64 + wave * 8;
  const float* sb = src + (size_t)(batch * NP + r0) * 3;
  float px[8], py[8], pz[8];
  #pragma unroll
  for (int r = 0; r < 8; ++r) {
    px[r] = sb[3*r+0]; py[r] = sb[3*r+1]; pz[r] = sb[3*r+2];
  }

  float Rtot[9] = {1.f,0.f,0.f, 0.f,1.f,0.f, 0.f,0.f,1.f};
  float ttot[3] = {0.f,0.f,0.f};

  for (int round = 0; round < NITER; ++round) {
    const int      par  = round & 1;
    const unsigned want = (unsigned)(round + 1);

    // ---- KNN via score = 0.5|t|^2 - p.t  (argmin(score) == argmin(dist)) ----
    float bs[8]; int bj[8];
    #pragma unroll
    for (int r = 0; r < 8; ++r) { bs[r] = 3.4e38f; bj[r] = 0; }
    #pragma unroll 4
    for (int k = 0; k < TSTEPS; ++k) {
      const int j = k * 64 + lane;
      const float4 tp = s_tgt[j];
      #pragma unroll
      for (int r = 0; r < 8; ++r) {
        const float sc = fmaf(-px[r], tp.x, fmaf(-py[r], tp.y, fmaf(-pz[r], tp.z, tp.w)));
        if (sc < bs[r]) { bs[r] = sc; bj[r] = j; }   // strict < keeps first index
      }
    }
    // cross-lane argmin, tie -> smaller index (matches argmin first-index rule)
    #pragma unroll
    for (int r = 0; r < 8; ++r) {
      #pragma unroll
      for (int sh = 0; sh < 6; ++sh) {
        const int   off = 32 >> sh;
        const float od  = __shfl_xor(bs[r], off);
        const int   oj  = __shfl_xor(bj[r], off);
        if (od < bs[r] || (od == bs[r] && oj < bj[r])) { bs[r] = od; bj[r] = oj; }
      }
    }

    // ---- per-wave Kabsch partials (identical in every lane; lane 0 writes) ----
    {
      float S[15];
      #pragma unroll
      for (int i = 0; i < 15; ++i) S[i] = 0.f;
      #pragma unroll
      for (int r = 0; r < 8; ++r) {
        const float4 tm = s_tgt[bj[r]];
        S[0]+=px[r]; S[1]+=py[r]; S[2]+=pz[r];
        S[3]+=tm.x;  S[4]+=tm.y;  S[5]+=tm.z;
        S[6] +=tm.x*px[r]; S[7] +=tm.x*py[r]; S[8] +=tm.x*pz[r];
        S[9] +=tm.y*px[r]; S[10]+=tm.y*py[r]; S[11]+=tm.y*pz[r];
        S[12]+=tm.z*px[r]; S[13]+=tm.z*py[r]; S[14]+=tm.z*pz[r];
      }
      if (lane == 0) {
        #pragma unroll
        for (int i = 0; i < 15; ++i) s_part[wave][i] = S[i];
      }
    }
    __syncthreads();

    if (wave == 0) {
      // fold 8 wave-partials: every lane ends with S_total[lane & 15]
      const int comp = lane & 15, grp = lane >> 4;
      float v = (comp < 15) ? (s_part[2*grp][comp] + s_part[2*grp+1][comp]) : 0.f;
      v += __shfl_xor(v, 16);
      v += __shfl_xor(v, 32);

      // publish own slot as 5 self-validating quarters {3 data, tag}.
      // Shuffles done by all lanes (uniform) before the divergent store.
      const int qi = (lane < 5) ? lane : 0;
      const float qx = __shfl(v, 3*qi + 0);
      const float qy = __shfl(v, 3*qi + 1);
      const float qz = __shfl(v, 3*qi + 2);
      float* slot = ws + (((size_t)batch * 2 + par) * TEAM + rank) * SLOTF;
      if (lane < 5) {
        st_q16(slot + 4*lane, qx, qy, qz, want);   // fire-and-forget; reader validates
      }

      // redundant reduce in every WG (last round: lead only)
      if ((round < NITER - 1) || lead) {
        float* sbase = ws + (((size_t)batch * 2 + par) * TEAM) * SLOTF;
        const float* slotq = sbase + (size_t)(lane & (TEAM-1)) * SLOTF;
        float4 a4, b4, c4, d4, e4;
        int ok, guard = 0;
        do {
          if (lane < TEAM) ld_slot5(slotq, a4, b4, c4, d4, e4);
          ok = (lane >= TEAM) ||
               (__float_as_uint(a4.w) == want && __float_as_uint(b4.w) == want &&
                __float_as_uint(c4.w) == want && __float_as_uint(d4.w) == want &&
                __float_as_uint(e4.w) == want);
          if (++guard > (1 << 15)) break;   // fail visibly, never wedge
        } while (!__all(ok));

        float s[15] = { a4.x,a4.y,a4.z, b4.x,b4.y,b4.z, c4.x,c4.y,c4.z,
                        d4.x,d4.y,d4.z, e4.x,e4.y,e4.z };
        if (lane >= TEAM) {
          #pragma unroll
          for (int i = 0; i < 15; ++i) s[i] = 0.f;
        }
        #pragma unroll
        for (int i = 0; i < 15; ++i) {
          s[i] += __shfl_xor(s[i], 1);
          s[i] += __shfl_xor(s[i], 2);
          s[i] += __shfl_xor(s[i], 4);
          s[i] += __shfl_xor(s[i], 8);
          s[i] += __shfl_xor(s[i], 16);
        }

        if (lane == 0) {
          const double inv = 1.0 / (double)NP;
          const double cs0=(double)s[0]*inv, cs1=(double)s[1]*inv, cs2=(double)s[2]*inv;
          const double ct0=(double)s[3]*inv, ct1=(double)s[4]*inv, ct2=(double)s[5]*inv;
          float M[9];
          M[0]=(float)((double)s[6] -(double)NP*ct0*cs0); M[1]=(float)((double)s[7] -(double)NP*ct0*cs1); M[2]=(float)((double)s[8] -(double)NP*ct0*cs2);
          M[3]=(float)((double)s[9] -(double)NP*ct1*cs0); M[4]=(float)((double)s[10]-(double)NP*ct1*cs1); M[5]=(float)((double)s[11]-(double)NP*ct1*cs2);
          M[6]=(float)((double)s[12]-(double)NP*ct2*cs0); M[7]=(float)((double)s[13]-(double)NP*ct2*cs1); M[8]=(float)((double)s[14]-(double)NP*ct2*cs2);
          float R[9]; polar3x3f(M, R);
          const float t0 = (float)(ct0 - ((double)R[0]*cs0 + (double)R[1]*cs1 + (double)R[2]*cs2));
          const float t1 = (float)(ct1 - ((double)R[3]*cs0 + (double)R[4]*cs1 + (double)R[5]*cs2));
          const float t2 = (float)(ct2 - ((double)R[6]*cs0 + (double)R[7]*cs1 + (double)R[8]*cs2));

          s_rt[0]=R[0]; s_rt[1]=R[1]; s_rt[2]=R[2];
          s_rt[3]=R[3]; s_rt[4]=R[4]; s_rt[5]=R[5];
          s_rt[6]=R[6]; s_rt[7]=R[7]; s_rt[8]=R[8];
          s_rt[9]=t0;  s_rt[10]=t1;  s_rt[11]=t2;

          if (lead) {
            // compose total transform: T_tot <- T_round ∘ T_tot
            float Rn[9], tn[3];
            #pragma unroll
            for (int i = 0; i < 3; ++i) {
              Rn[3*i+0] = R[3*i+0]*Rtot[0] + R[3*i+1]*Rtot[3] + R[3*i+2]*Rtot[6];
              Rn[3*i+1] = R[3*i+0]*Rtot[1] + R[3*i+1]*Rtot[4] + R[3*i+2]*Rtot[7];
              Rn[3*i+2] = R[3*i+0]*Rtot[2] + R[3*i+1]*Rtot[5] + R[3*i+2]*Rtot[8];
              tn[i]     = R[3*i+0]*ttot[0] + R[3*i+1]*ttot[1] + R[3*i+2]*ttot[2]
                        + ((i==0)?t0:(i==1)?t1:t2);
            }
            #pragma unroll
            for (int i = 0; i < 9; ++i) Rtot[i] = Rn[i];
            ttot[0]=tn[0]; ttot[1]=tn[1]; ttot[2]=tn[2];

            if (round == NITER - 1) {
              // svdtf(source, temporal_8) == composed transform (exact rigid,
              // det=+1, so the reference's reflection branch is a no-op)
              float* ob = out + batch * 12;
              ob[0]=Rtot[0]; ob[1]=Rtot[1]; ob[2] =Rtot[2]; ob[3] =ttot[0];
              ob[4]=Rtot[3]; ob[5]=Rtot[4]; ob[6] =Rtot[5]; ob[7] =ttot[1];
              ob[8]=Rtot[6]; ob[9]=Rtot[7]; ob[10]=Rtot[8]; ob[11]=ttot[2];
            }
          }
        }
      }
    }

    if (round < NITER - 1) {
      __syncthreads();
      // ---- apply transform to this wave's temporal points (fp32, like ref) ----
      const float R00=s_rt[0],R01=s_rt[1],R02=s_rt[2],
                  R10=s_rt[3],R11=s_rt[4],R12=s_rt[5],
                  R20=s_rt[6],R21=s_rt[7],R22=s_rt[8],
                  t0=s_rt[9], t1=s_rt[10], t2=s_rt[11];
      #pragma unroll
      for (int r = 0; r < 8; ++r) {
        const float nx = t0 + R00*px[r] + R01*py[r] + R02*pz[r];
        const float ny = t1 + R10*px[r] + R11*py[r] + R12*pz[r];
        const float nz = t2 + R20*px[r] + R21*py[r] + R22*pz[r];
        px[r]=nx; py[r]=ny; pz[r]=nz;
      }
    }
    // last round: publish only; lead composes and writes the output.
  }
}

extern "C" void kernel_launch(void* const* d_in, const int* in_sizes, int n_in,
                              void* d_out, int out_size, void* d_ws, size_t ws_size,
                              hipStream_t stream)
{
  const float* src = (const float*)d_in[0];
  const float* tgt = (const float*)d_in[1];
  float* out = (float*)d_out;
  float* ws  = (float*)d_ws;

  // zero slots + rank counters each call: deterministic across graph replays
  (void)hipMemsetAsync(d_ws, 0, WS_FLOATS * sizeof(float), stream);

  void* args[] = { (void*)&src, (void*)&tgt, (void*)&out, (void*)&ws };
  (void)hipLaunchCooperativeKernel(reinterpret_cast<void*>(icp_kernel),
                                   dim3(NWG), dim3(NT), args, 0, stream);
}

// Round 12
// 138.307 us; speedup vs baseline: 1.4578x; 1.0317x over previous
//
#include <hip/hip_runtime.h>

#define NB     8      // batches
#define NP     2048   // points per cloud
#define NITER  8
#define TEAM   32     // WGs per XCD-team (1 WG/CU enforced => exactly 32 WGs/XCD)
#define NWG    256    // cooperative grid (1 WG per CU)
#define NT     512    // threads per workgroup (8 waves)
#define TSTEPS 32     // targets per lane = NP / 64
#define SLOTF  20     // floats per slot: 5 x 16B self-validating quarters

// ws float layout:
//   slots : [NB][2 parity][TEAM][SLOTF]  (5 quarters {d0,d1,d2,tag} each)
//   reg   : 8 uints (per-XCD rank counters, relaxed agent fetch_add)
// NO memset needed (R12):
//  - ranks: fetch_add returns 32 consecutive values from ANY start (0xAA.. or
//    accumulated across replays); &31 is a bijection onto 0..31. Rank->refs
//    assignment is permutation-invariant for the reduce (slots indexed by
//    rank), so results are bitwise-deterministic regardless of WG ordering.
//  - tags: poison 0xAAAAAAAA != want (1..8) -> "not ready". Stale tags from a
//    prior replay are zeroed by the LEAD at kernel end, after its final reduce
//    has OBSERVED all tags (so every slot store is visible -> race-free).
#define SLOTS_FLOATS (NB*2*TEAM*SLOTF)   // 10240
#define REG_FBASE    SLOTS_FLOATS
#define WS_FLOATS    (REG_FBASE + 8)

typedef float f32x4 __attribute__((ext_vector_type(4)));

// Comm protocol: TAG-EMBEDDED 16B units at sc0+sc1 (== volatile) scope.
// A dwordx4 store is one 16B transaction, so each quarter {3 floats, tag} is
// self-validating: a load that sees the tag sees its data. No writer waitcnt,
// no separate tag store, no second gather round trip. (R8/R9 split tag/data
// plain-store protocol raced; abandoned. Inline-asm can't take float4 INPUT
// operands on gfx950 clang -> volatile ext_vector store emits the same
// global_store_dwordx4 sc0 sc1.)
__device__ __forceinline__ void st_q16(float* p, float x, float y, float z, unsigned tag) {
  f32x4 v = { x, y, z, __uint_as_float(tag) };
  *(volatile f32x4*)p = v;
}
__device__ __forceinline__ void ld_slot5(const float* p, float4& a, float4& b,
                                         float4& c, float4& d, float4& e) {
  asm volatile("global_load_dwordx4 %0, %5, off sc0 sc1\n\t"
               "global_load_dwordx4 %1, %5, off offset:16 sc0 sc1\n\t"
               "global_load_dwordx4 %2, %5, off offset:32 sc0 sc1\n\t"
               "global_load_dwordx4 %3, %5, off offset:48 sc0 sc1\n\t"
               "global_load_dwordx4 %4, %5, off offset:64 sc0 sc1\n\t"
               "s_waitcnt vmcnt(0)"
               : "=&v"(a), "=&v"(b), "=&v"(c), "=&v"(d), "=&v"(e)
               : "v"(p) : "memory");
}

// Orthogonal polar factor of M (== U @ Vh of the SVD) in fp32, with the
// reference's reflection handling (R = -R when det = -1). Det-scaled Newton.
// 12 iterations: proven floor (absmax 7.6e-6). Do NOT trim (R8: 10 iters ->
// 4.3e-2).
__device__ void polar3x3f(const float* Min, float* R) {
  float X[9];
  #pragma unroll
  for (int i = 0; i < 9; ++i) X[i] = Min[i];
  #pragma unroll 1
  for (int it = 0; it < 12; ++it) {
    const float C0 = X[4]*X[8]-X[5]*X[7];
    const float C1 = X[5]*X[6]-X[3]*X[8];
    const float C2 = X[3]*X[7]-X[4]*X[6];
    const float C3 = X[2]*X[7]-X[1]*X[8];
    const float C4 = X[0]*X[8]-X[2]*X[6];
    const float C5 = X[1]*X[6]-X[0]*X[7];
    const float C6 = X[1]*X[5]-X[2]*X[4];
    const float C7 = X[2]*X[3]-X[0]*X[5];
    const float C8 = X[0]*X[4]-X[1]*X[3];
    const float det = X[0]*C0 + X[1]*C1 + X[2]*C2;
    const float ad  = fabsf(det);
    const float g   = (ad > 1e-30f) ? exp2f(-0.33333333333f * log2f(ad)) : 1.0f;
    const float ds  = (ad > 1e-30f) ? det : 1e-30f;
    const float h   = 0.5f / (g * ds);     // X' = 0.5*g*X + cof(X)/(2*g*det)
    const float gh  = 0.5f * g;
    X[0]=gh*X[0]+h*C0; X[1]=gh*X[1]+h*C1; X[2]=gh*X[2]+h*C2;
    X[3]=gh*X[3]+h*C3; X[4]=gh*X[4]+h*C4; X[5]=gh*X[5]+h*C5;
    X[6]=gh*X[6]+h*C6; X[7]=gh*X[7]+h*C7; X[8]=gh*X[8]+h*C8;
  }
  const float d = X[0]*(X[4]*X[8]-X[5]*X[7])
                + X[1]*(X[5]*X[6]-X[3]*X[8])
                + X[2]*(X[3]*X[7]-X[4]*X[6]);
  const float s = (d < 0.0f) ? -1.0f : 1.0f;
  #pragma unroll
  for (int i = 0; i < 9; ++i) R[i] = s * X[i];
}

__global__ __launch_bounds__(NT)
__attribute__((amdgpu_waves_per_eu(2, 2)))   // cap 8 waves/CU -> exactly 1 WG/CU
void icp_kernel(const float* __restrict__ src, const float* __restrict__ tgt,
                float* __restrict__ out, float* __restrict__ ws)
{
  __shared__ float4 s_tgt[NP];        // 32 KB: {x,y,z, 0.5*|t|^2}
  __shared__ float  s_part[8][16];    // per-wave partial sums
  __shared__ float  s_rt[12];         // R (9) + t (3) broadcast within WG
  __shared__ int    s_rank;

  const int tid  = threadIdx.x;
  const int wave = tid >> 6;
  const int lane = tid & 63;

  // XCD id (wave-uniform scalar; identical across the WG's waves)
  unsigned xcc;
  asm volatile("s_getreg_b32 %0, hwreg(HW_REG_XCC_ID)" : "=s"(xcc));
  const int batch = (int)(xcc & 7u);  // team == XCD == batch (1:1, 8 each)

  // rank: relaxed fetch_add on THIS XCD's counter. No reset needed: 32
  // consecutive returns & 31 is a bijection onto 0..31 from any start value.
  if (tid == 0) {
    unsigned* reg = (unsigned*)(ws + REG_FBASE);
    const unsigned rk =
        __hip_atomic_fetch_add(&reg[batch], 1u, __ATOMIC_RELAXED, __HIP_MEMORY_SCOPE_AGENT);
    s_rank = (int)(rk & 31u);
  }

  // ---- stage targets; .w = 0.5*|t|^2 for the score trick ----
  const float* tb = tgt + (size_t)batch * NP * 3;
  for (int i = tid; i < NP; i += NT) {
    const float tx = tb[3*i+0], ty = tb[3*i+1], tz = tb[3*i+2];
    s_tgt[i] = make_float4(tx, ty, tz, 0.5f*(tx*tx + ty*ty + tz*tz));
  }
  __syncthreads();

  const int  rank = s_rank;           // 0..31 within this XCD's team
  const bool lead = (rank == 0);

  // ---- this wave's 8 temporal points (replicated across lanes, registers) ----
  const int r0 = rank * 64 + wave * 8;
  const float* sb = src + (size_t)(batch * NP + r0) * 3;
  float px[8], py[8], pz[8];
  #pragma unroll
  for (int r = 0; r < 8; ++r) {
    px[r] = sb[3*r+0]; py[r] = sb[3*r+1]; pz[r] = sb[3*r+2];
  }

  float Rtot[9] = {1.f,0.f,0.f, 0.f,1.f,0.f, 0.f,0.f,1.f};
  float ttot[3] = {0.f,0.f,0.f};

  for (int round = 0; round < NITER; ++round) {
    const int      par  = round & 1;
    const unsigned want = (unsigned)(round + 1);

    // ---- KNN via score = 0.5|t|^2 - p.t  (argmin(score) == argmin(dist)) ----
    float bs[8]; int bj[8];
    #pragma unroll
    for (int r = 0; r < 8; ++r) { bs[r] = 3.4e38f; bj[r] = 0; }
    #pragma unroll 4
    for (int k = 0; k < TSTEPS; ++k) {
      const int j = k * 64 + lane;
      const float4 tp = s_tgt[j];
      #pragma unroll
      for (int r = 0; r < 8; ++r) {
        const float sc = fmaf(-px[r], tp.x, fmaf(-py[r], tp.y, fmaf(-pz[r], tp.z, tp.w)));
        if (sc < bs[r]) { bs[r] = sc; bj[r] = j; }   // strict < keeps first index
      }
    }
    // cross-lane argmin, tie -> smaller index (matches argmin first-index rule)
    #pragma unroll
    for (int r = 0; r < 8; ++r) {
      #pragma unroll
      for (int sh = 0; sh < 6; ++sh) {
        const int   off = 32 >> sh;
        const float od  = __shfl_xor(bs[r], off);
        const int   oj  = __shfl_xor(bj[r], off);
        if (od < bs[r] || (od == bs[r] && oj < bj[r])) { bs[r] = od; bj[r] = oj; }
      }
    }

    // ---- per-wave Kabsch partials (identical in every lane; lane 0 writes) ----
    {
      float S[15];
      #pragma unroll
      for (int i = 0; i < 15; ++i) S[i] = 0.f;
      #pragma unroll
      for (int r = 0; r < 8; ++r) {
        const float4 tm = s_tgt[bj[r]];
        S[0]+=px[r]; S[1]+=py[r]; S[2]+=pz[r];
        S[3]+=tm.x;  S[4]+=tm.y;  S[5]+=tm.z;
        S[6] +=tm.x*px[r]; S[7] +=tm.x*py[r]; S[8] +=tm.x*pz[r];
        S[9] +=tm.y*px[r]; S[10]+=tm.y*py[r]; S[11]+=tm.y*pz[r];
        S[12]+=tm.z*px[r]; S[13]+=tm.z*py[r]; S[14]+=tm.z*pz[r];
      }
      if (lane == 0) {
        #pragma unroll
        for (int i = 0; i < 15; ++i) s_part[wave][i] = S[i];
      }
    }
    __syncthreads();

    if (wave == 0) {
      // fold 8 wave-partials: every lane ends with S_total[lane & 15]
      const int comp = lane & 15, grp = lane >> 4;
      float v = (comp < 15) ? (s_part[2*grp][comp] + s_part[2*grp+1][comp]) : 0.f;
      v += __shfl_xor(v, 16);
      v += __shfl_xor(v, 32);

      // publish own slot as 5 self-validating quarters {3 data, tag}.
      // Shuffles done by all lanes (uniform) before the divergent store.
      const int qi = (lane < 5) ? lane : 0;
      const float qx = __shfl(v, 3*qi + 0);
      const float qy = __shfl(v, 3*qi + 1);
      const float qz = __shfl(v, 3*qi + 2);
      float* slot = ws + (((size_t)batch * 2 + par) * TEAM + rank) * SLOTF;
      if (lane < 5) {
        st_q16(slot + 4*lane, qx, qy, qz, want);   // fire-and-forget; reader validates
      }

      // redundant reduce in every WG (last round: lead only)
      if ((round < NITER - 1) || lead) {
        float* sbase = ws + (((size_t)batch * 2 + par) * TEAM) * SLOTF;
        const float* slotq = sbase + (size_t)(lane & (TEAM-1)) * SLOTF;
        float4 a4, b4, c4, d4, e4;
        int ok, guard = 0;
        do {
          if (lane < TEAM) ld_slot5(slotq, a4, b4, c4, d4, e4);
          ok = (lane >= TEAM) ||
               (__float_as_uint(a4.w) == want && __float_as_uint(b4.w) == want &&
                __float_as_uint(c4.w) == want && __float_as_uint(d4.w) == want &&
                __float_as_uint(e4.w) == want);
          if (++guard > (1 << 15)) break;   // fail visibly, never wedge
        } while (!__all(ok));

        float s[15] = { a4.x,a4.y,a4.z, b4.x,b4.y,b4.z, c4.x,c4.y,c4.z,
                        d4.x,d4.y,d4.z, e4.x,e4.y,e4.z };
        if (lane >= TEAM) {
          #pragma unroll
          for (int i = 0; i < 15; ++i) s[i] = 0.f;
        }
        #pragma unroll
        for (int i = 0; i < 15; ++i) {
          s[i] += __shfl_xor(s[i], 1);
          s[i] += __shfl_xor(s[i], 2);
          s[i] += __shfl_xor(s[i], 4);
          s[i] += __shfl_xor(s[i], 8);
          s[i] += __shfl_xor(s[i], 16);
        }

        if (lane == 0) {
          const double inv = 1.0 / (double)NP;
          const double cs0=(double)s[0]*inv, cs1=(double)s[1]*inv, cs2=(double)s[2]*inv;
          const double ct0=(double)s[3]*inv, ct1=(double)s[4]*inv, ct2=(double)s[5]*inv;
          float M[9];
          M[0]=(float)((double)s[6] -(double)NP*ct0*cs0); M[1]=(float)((double)s[7] -(double)NP*ct0*cs1); M[2]=(float)((double)s[8] -(double)NP*ct0*cs2);
          M[3]=(float)((double)s[9] -(double)NP*ct1*cs0); M[4]=(float)((double)s[10]-(double)NP*ct1*cs1); M[5]=(float)((double)s[11]-(double)NP*ct1*cs2);
          M[6]=(float)((double)s[12]-(double)NP*ct2*cs0); M[7]=(float)((double)s[13]-(double)NP*ct2*cs1); M[8]=(float)((double)s[14]-(double)NP*ct2*cs2);
          float R[9]; polar3x3f(M, R);
          const float t0 = (float)(ct0 - ((double)R[0]*cs0 + (double)R[1]*cs1 + (double)R[2]*cs2));
          const float t1 = (float)(ct1 - ((double)R[3]*cs0 + (double)R[4]*cs1 + (double)R[5]*cs2));
          const float t2 = (float)(ct2 - ((double)R[6]*cs0 + (double)R[7]*cs1 + (double)R[8]*cs2));

          s_rt[0]=R[0]; s_rt[1]=R[1]; s_rt[2]=R[2];
          s_rt[3]=R[3]; s_rt[4]=R[4]; s_rt[5]=R[5];
          s_rt[6]=R[6]; s_rt[7]=R[7]; s_rt[8]=R[8];
          s_rt[9]=t0;  s_rt[10]=t1;  s_rt[11]=t2;

          if (lead) {
            // compose total transform: T_tot <- T_round ∘ T_tot
            float Rn[9], tn[3];
            #pragma unroll
            for (int i = 0; i < 3; ++i) {
              Rn[3*i+0] = R[3*i+0]*Rtot[0] + R[3*i+1]*Rtot[3] + R[3*i+2]*Rtot[6];
              Rn[3*i+1] = R[3*i+0]*Rtot[1] + R[3*i+1]*Rtot[4] + R[3*i+2]*Rtot[7];
              Rn[3*i+2] = R[3*i+0]*Rtot[2] + R[3*i+1]*Rtot[5] + R[3*i+2]*Rtot[8];
              tn[i]     = R[3*i+0]*ttot[0] + R[3*i+1]*ttot[1] + R[3*i+2]*ttot[2]
                        + ((i==0)?t0:(i==1)?t1:t2);
            }
            #pragma unroll
            for (int i = 0; i < 9; ++i) Rtot[i] = Rn[i];
            ttot[0]=tn[0]; ttot[1]=tn[1]; ttot[2]=tn[2];

            if (round == NITER - 1) {
              // svdtf(source, temporal_8) == composed transform (exact rigid,
              // det=+1, so the reference's reflection branch is a no-op)
              float* ob = out + batch * 12;
              ob[0]=Rtot[0]; ob[1]=Rtot[1]; ob[2] =Rtot[2]; ob[3] =ttot[0];
              ob[4]=Rtot[3]; ob[5]=Rtot[4]; ob[6] =Rtot[5]; ob[7] =ttot[1];
              ob[8]=Rtot[6]; ob[9]=Rtot[7]; ob[10]=Rtot[8]; ob[11]=ttot[2];
            }
          }
        }
      }
    }

    if (round < NITER - 1) {
      __syncthreads();
      // ---- apply transform to this wave's temporal points (fp32, like ref) ----
      const float R00=s_rt[0],R01=s_rt[1],R02=s_rt[2],
                  R10=s_rt[3],R11=s_rt[4],R12=s_rt[5],
                  R20=s_rt[6],R21=s_rt[7],R22=s_rt[8],
                  t0=s_rt[9], t1=s_rt[10], t2=s_rt[11];
      #pragma unroll
      for (int r = 0; r < 8; ++r) {
        const float nx = t0 + R00*px[r] + R01*py[r] + R02*pz[r];
        const float ny = t1 + R10*px[r] + R11*py[r] + R12*pz[r];
        const float nz = t2 + R20*px[r] + R21*py[r] + R22*pz[r];
        px[r]=nx; py[r]=ny; pz[r]=nz;
      }
    }
    // last round: publish only; lead composes and writes the output.
  }

  // ---- lead end-of-kernel cleanup: zero all 64 slot tags of this batch ----
  // Safe: lead's final reduce OBSERVED parity-1 tags==8 (round 7) and, in
  // round 6, parity-0 tags==7 — so every slot store is visible before these
  // zero stores. No WG reads slots after its final publish. Next replay then
  // starts with tags==0 ("not ready"), making the kernel memset-free.
  if (lead && wave == 0) {
    float* base = ws + ((size_t)batch * 2) * TEAM * SLOTF;
    unsigned* slotTags = (unsigned*)(base + (size_t)lane * SLOTF);
    #pragma unroll
    for (int q = 0; q < 5; ++q)
      *(volatile unsigned*)(slotTags + 4*q + 3) = 0u;
  }
}

extern "C" void kernel_launch(void* const* d_in, const int* in_sizes, int n_in,
                              void* d_out, int out_size, void* d_ws, size_t ws_size,
                              hipStream_t stream)
{
  const float* src = (const float*)d_in[0];
  const float* tgt = (const float*)d_in[1];
  float* out = (float*)d_out;
  float* ws  = (float*)d_ws;

  // No memset: ranks are bijective from any counter start; tags are
  // self-cleaning (lead zeroes at kernel end; 0xAA poison reads as not-ready).
  void* args[] = { (void*)&src, (void*)&tgt, (void*)&out, (void*)&ws };
  (void)hipLaunchCooperativeKernel(reinterpret_cast<void*>(icp_kernel),
                                   dim3(NWG), dim3(NT), args, 0, stream);
}